// Round 1
// baseline (685.794 us; speedup 1.0000x reference)
//
#include <hip/hip_runtime.h>

// GCN 2-layer: 256 -> 16 -> 1, N=100000 nodes, E=3.2M edges + self loops.
// Factorization: out[d] = isq[d] * sum_{e: dst=d} (h[src]*isq[src]) + b
// Self-loop handled by initializing the aggregation buffer with the node's
// own scaled value (src=dst=n edge).

__global__ void k_deg(const int* __restrict__ dst, int E, int* __restrict__ deg) {
    int e = blockIdx.x * blockDim.x + threadIdx.x;
    if (e < E) atomicAdd(&deg[dst[e]], 1);
}

__global__ void k_isq(const int* __restrict__ deg, float* __restrict__ isq, int N) {
    int n = blockIdx.x * blockDim.x + threadIdx.x;
    if (n < N) isq[n] = rsqrtf((float)(deg[n] + 1));   // +1 = self loop
}

// hs[n][f] = dot(x[n,:], W1[:,f]) * isq[n]; agg1 initialized to hs (self loop).
// Block = 256 threads = 16 nodes x 16 features. x tile + transposed W1 in LDS.
__global__ __launch_bounds__(256) void k_lin1(
    const float* __restrict__ x, const float* __restrict__ W1,
    const float* __restrict__ isq, float* __restrict__ hs,
    float* __restrict__ agg1, int N, int ntiles)
{
    __shared__ float xs[16][260];   // +4 pad: float4-aligned rows, bank-shifted
    __shared__ float wT[16][260];   // W1 transposed: wT[f][k]
    const int t = threadIdx.x;
    #pragma unroll
    for (int i = 0; i < 16; ++i) {
        int idx = t + i * 256;               // 4096 elements of W1 [256][16]
        wT[idx & 15][idx >> 4] = W1[idx];
    }
    const int ln = t >> 4, f = t & 15;
    for (int tile = blockIdx.x; tile < ntiles; tile += gridDim.x) {
        const int n0 = tile << 4;
        __syncthreads();                     // xs reuse from previous tile
        #pragma unroll
        for (int i = 0; i < 16; ++i) {
            int idx = t + i * 256;           // 16 rows x 256 cols, coalesced
            int r = idx >> 8, k = idx & 255;
            int n = n0 + r;
            xs[r][k] = (n < N) ? x[(size_t)n * 256 + k] : 0.f;
        }
        __syncthreads();
        const int n = n0 + ln;
        const float4* xr = (const float4*)(&xs[ln][0]);
        const float4* wr = (const float4*)(&wT[f][0]);
        float acc = 0.f;
        #pragma unroll 8
        for (int k4 = 0; k4 < 64; ++k4) {
            float4 a = xr[k4];
            float4 b = wr[k4];
            acc += a.x * b.x + a.y * b.y + a.z * b.z + a.w * b.w;
        }
        if (n < N) {
            float v = acc * isq[n];
            hs[n * 16 + f]   = v;
            agg1[n * 16 + f] = v;            // self-loop contribution
        }
    }
}

// One thread per (edge, feature): lanes f=0..15 gather a coalesced 64B row of
// hs[src] and atomically add into the 64B row of agg1[dst].
__global__ void k_agg1(const int* __restrict__ src, const int* __restrict__ dst,
                       const float* __restrict__ hs, float* __restrict__ agg1, int E) {
    int idx = blockIdx.x * blockDim.x + threadIdx.x;   // E*16 = 51.2M < 2^31
    int e = idx >> 4;
    if (e < E) {
        int f = idx & 15;
        int s = src[e], d = dst[e];
        atomicAdd(&agg1[d * 16 + f], hs[s * 16 + f]);
    }
}

// z[n] = isq[n] * sum_f relu(agg1[n][f]*isq[n] + b1[f]) * W2[f]; agg2 init = z.
__global__ void k_z(const float* __restrict__ agg1, const float* __restrict__ isq,
                    const float* __restrict__ b1, const float* __restrict__ W2,
                    float* __restrict__ z, float* __restrict__ agg2, int N) {
    int n = blockIdx.x * blockDim.x + threadIdx.x;
    if (n >= N) return;
    float iq = isq[n];
    float acc = 0.f;
    const float4* a4 = (const float4*)(&agg1[n * 16]);
    #pragma unroll
    for (int q = 0; q < 4; ++q) {
        float4 a = a4[q];
        float t0 = fmaxf(a.x * iq + b1[q * 4 + 0], 0.f);
        float t1 = fmaxf(a.y * iq + b1[q * 4 + 1], 0.f);
        float t2 = fmaxf(a.z * iq + b1[q * 4 + 2], 0.f);
        float t3 = fmaxf(a.w * iq + b1[q * 4 + 3], 0.f);
        acc += t0 * W2[q * 4 + 0] + t1 * W2[q * 4 + 1]
             + t2 * W2[q * 4 + 2] + t3 * W2[q * 4 + 3];
    }
    float zv = acc * iq;
    z[n] = zv;
    agg2[n] = zv;                            // self-loop contribution
}

__global__ void k_agg2(const int* __restrict__ src, const int* __restrict__ dst,
                       const float* __restrict__ z, float* __restrict__ agg2, int E) {
    int e = blockIdx.x * blockDim.x + threadIdx.x;
    if (e < E) atomicAdd(&agg2[dst[e]], z[src[e]]);
}

__global__ void k_out(const float* __restrict__ agg2, const float* __restrict__ isq,
                      const float* __restrict__ b2, float* __restrict__ out, int N) {
    int n = blockIdx.x * blockDim.x + threadIdx.x;
    if (n < N) out[n] = agg2[n] * isq[n] + b2[0];
}

extern "C" void kernel_launch(void* const* d_in, const int* in_sizes, int n_in,
                              void* d_out, int out_size, void* d_ws, size_t ws_size,
                              hipStream_t stream) {
    const float* x  = (const float*)d_in[0];
    const int*   ei = (const int*)d_in[1];
    const float* W1 = (const float*)d_in[2];
    const float* b1 = (const float*)d_in[3];
    const float* W2 = (const float*)d_in[4];
    const float* b2 = (const float*)d_in[5];
    const int N = in_sizes[0] / 256;
    const int E = in_sizes[1] / 2;
    const int* src = ei;
    const int* dst = ei + E;

    // workspace layout (all 16B aligned; N*4 = 400000 is a multiple of 16)
    char* w = (char*)d_ws;
    int*   deg  = (int*)w;   w += (size_t)N * 4;
    float* isq  = (float*)w; w += (size_t)N * 4;
    float* hs   = (float*)w; w += (size_t)N * 64;
    float* agg1 = (float*)w; w += (size_t)N * 64;
    float* z    = (float*)w; w += (size_t)N * 4;
    float* agg2 = (float*)w; w += (size_t)N * 4;
    float* out  = (float*)d_out;

    hipMemsetAsync(deg, 0, (size_t)N * 4, stream);
    k_deg<<<(E + 255) / 256, 256, 0, stream>>>(dst, E, deg);
    k_isq<<<(N + 255) / 256, 256, 0, stream>>>(deg, isq, N);

    const int ntiles = (N + 15) / 16;
    const int grid1 = ntiles < 2048 ? ntiles : 2048;
    k_lin1<<<grid1, 256, 0, stream>>>(x, W1, isq, hs, agg1, N, ntiles);

    const long long tot = (long long)E * 16;
    k_agg1<<<(int)((tot + 255) / 256), 256, 0, stream>>>(src, dst, hs, agg1, E);
    k_z<<<(N + 255) / 256, 256, 0, stream>>>(agg1, isq, b1, W2, z, agg2, N);
    k_agg2<<<(E + 255) / 256, 256, 0, stream>>>(src, dst, z, agg2, E);
    k_out<<<(N + 255) / 256, 256, 0, stream>>>(agg2, isq, b2, out, N);
}

// Round 2
// 581.808 us; speedup vs baseline: 1.1787x; 1.1787x over previous
//
#include <hip/hip_runtime.h>

// GCN 2-layer: 256 -> 16 -> 1, N=100000 nodes, E=3.2M edges + self loops.
// R2: CSR gather aggregation (no float atomics).
//   out[d] = isq[d] * sum_{e: dst=d} (h[src]*isq[src]) + b ; self loop = own value.
// Pipeline: deg histogram -> isq -> scan(rowp) -> scatter(csr) -> lin1(hs) ->
//           gather1(fused relu+W2 -> z) -> gather2(fused epilogue -> out).

__global__ void k_deg(const int* __restrict__ dst, int E, int* __restrict__ deg) {
    int e = blockIdx.x * blockDim.x + threadIdx.x;
    if (e < E) atomicAdd(&deg[dst[e]], 1);
}

__global__ void k_isq(const int* __restrict__ deg, float* __restrict__ isq, int N) {
    int n = blockIdx.x * blockDim.x + threadIdx.x;
    if (n < N) isq[n] = rsqrtf((float)(deg[n] + 1));   // +1 = self loop
}

// ---- exclusive scan of deg[N] -> rowp[N+1], 3 tiny kernels ----
__global__ void k_scan_bsum(const int* __restrict__ deg, int N, int* __restrict__ bsum) {
    __shared__ int s[256];
    int t = threadIdx.x, i = blockIdx.x * 256 + t;
    s[t] = (i < N) ? deg[i] : 0;
    __syncthreads();
    for (int off = 128; off > 0; off >>= 1) {
        if (t < off) s[t] += s[t + off];
        __syncthreads();
    }
    if (t == 0) bsum[blockIdx.x] = s[0];
}

__global__ void k_scan_boff(const int* __restrict__ bsum, int nb, int* __restrict__ boff) {
    __shared__ int s[512];
    int t = threadIdx.x;
    int v = (t < nb) ? bsum[t] : 0;
    s[t] = v;
    __syncthreads();
    for (int off = 1; off < 512; off <<= 1) {
        int x = (t >= off) ? s[t - off] : 0;
        __syncthreads();
        s[t] += x;
        __syncthreads();
    }
    if (t < nb) boff[t] = s[t] - v;   // exclusive
}

__global__ void k_scan_final(const int* __restrict__ deg, const int* __restrict__ boff,
                             int N, int E, int* __restrict__ rowp) {
    __shared__ int s[256];
    int t = threadIdx.x, i = blockIdx.x * 256 + t;
    int v = (i < N) ? deg[i] : 0;
    s[t] = v;
    __syncthreads();
    for (int off = 1; off < 256; off <<= 1) {
        int x = (t >= off) ? s[t - off] : 0;
        __syncthreads();
        s[t] += x;
        __syncthreads();
    }
    if (i < N) rowp[i] = boff[blockIdx.x] + s[t] - v;
    if (i == 0) rowp[N] = E;
}

__global__ void k_scatter(const int* __restrict__ src, const int* __restrict__ dst,
                          const int* __restrict__ rowp, int* __restrict__ cursor,
                          int* __restrict__ csr, int E) {
    int e = blockIdx.x * blockDim.x + threadIdx.x;
    if (e < E) {
        int d = dst[e];
        int pos = rowp[d] + atomicAdd(&cursor[d], 1);
        csr[pos] = src[e];
    }
}

// hs[n][f] = dot(x[n,:], W1[:,f]) * isq[n]
__global__ __launch_bounds__(256) void k_lin1(
    const float* __restrict__ x, const float* __restrict__ W1,
    const float* __restrict__ isq, float* __restrict__ hs, int N, int ntiles)
{
    __shared__ float xs[16][260];
    __shared__ float wT[16][260];
    const int t = threadIdx.x;
    #pragma unroll
    for (int i = 0; i < 16; ++i) {
        int idx = t + i * 256;               // 4096 elements of W1 [256][16]
        wT[idx & 15][idx >> 4] = W1[idx];
    }
    const int ln = t >> 4, f = t & 15;
    for (int tile = blockIdx.x; tile < ntiles; tile += gridDim.x) {
        const int n0 = tile << 4;
        __syncthreads();
        #pragma unroll
        for (int i = 0; i < 16; ++i) {
            int idx = t + i * 256;
            int r = idx >> 8, k = idx & 255;
            int n = n0 + r;
            xs[r][k] = (n < N) ? x[(size_t)n * 256 + k] : 0.f;
        }
        __syncthreads();
        const int n = n0 + ln;
        const float4* xr = (const float4*)(&xs[ln][0]);
        const float4* wr = (const float4*)(&wT[f][0]);
        float acc = 0.f;
        #pragma unroll 8
        for (int k4 = 0; k4 < 64; ++k4) {
            float4 a = xr[k4];
            float4 b = wr[k4];
            acc += a.x * b.x + a.y * b.y + a.z * b.z + a.w * b.w;
        }
        if (n < N) hs[n * 16 + f] = acc * isq[n];
    }
}

// Layer-1 gather + relu + W2 dot, fused. 16 lanes (features) per node.
// z[n] = isq[n] * sum_f relu( isq[n]*(hs[n][f] + sum_src hs[src][f]) + b1[f] ) * W2[f]
__global__ __launch_bounds__(256) void k_gather1(
    const int* __restrict__ rowp, const int* __restrict__ csr,
    const float* __restrict__ hs, const float* __restrict__ isq,
    const float* __restrict__ b1, const float* __restrict__ W2,
    float* __restrict__ z, int N)
{
    const int slot = threadIdx.x >> 4;
    const int f = threadIdx.x & 15;
    const int n = blockIdx.x * 16 + slot;
    if (n >= N) return;
    float acc = hs[n * 16 + f];              // self loop
    const int beg = rowp[n], end = rowp[n + 1];
    int j = beg;
    for (; j + 4 <= end; j += 4) {
        int s0 = csr[j], s1 = csr[j + 1], s2 = csr[j + 2], s3 = csr[j + 3];
        float a0 = hs[s0 * 16 + f];
        float a1 = hs[s1 * 16 + f];
        float a2 = hs[s2 * 16 + f];
        float a3 = hs[s3 * 16 + f];
        acc += (a0 + a1) + (a2 + a3);
    }
    for (; j < end; ++j) acc += hs[csr[j] * 16 + f];
    const float iq = isq[n];
    float h2 = fmaxf(acc * iq + b1[f], 0.f);
    float p = h2 * W2[f];
    p += __shfl_xor(p, 1, 16);
    p += __shfl_xor(p, 2, 16);
    p += __shfl_xor(p, 4, 16);
    p += __shfl_xor(p, 8, 16);
    if (f == 0) z[n] = p * iq;
}

// Layer-2 gather + epilogue: out[n] = isq[n]*(z[n] + sum_src z[src]) + b2
__global__ void k_gather2(const int* __restrict__ rowp, const int* __restrict__ csr,
                          const float* __restrict__ z, const float* __restrict__ isq,
                          const float* __restrict__ b2, float* __restrict__ out, int N) {
    int n = blockIdx.x * blockDim.x + threadIdx.x;
    if (n >= N) return;
    float acc = z[n];                        // self loop
    const int beg = rowp[n], end = rowp[n + 1];
    int j = beg;
    for (; j + 4 <= end; j += 4) {
        int s0 = csr[j], s1 = csr[j + 1], s2 = csr[j + 2], s3 = csr[j + 3];
        acc += (z[s0] + z[s1]) + (z[s2] + z[s3]);
    }
    for (; j < end; ++j) acc += z[csr[j]];
    out[n] = acc * isq[n] + b2[0];
}

extern "C" void kernel_launch(void* const* d_in, const int* in_sizes, int n_in,
                              void* d_out, int out_size, void* d_ws, size_t ws_size,
                              hipStream_t stream) {
    const float* x  = (const float*)d_in[0];
    const int*   ei = (const int*)d_in[1];
    const float* W1 = (const float*)d_in[2];
    const float* b1 = (const float*)d_in[3];
    const float* W2 = (const float*)d_in[4];
    const float* b2 = (const float*)d_in[5];
    const int N = in_sizes[0] / 256;
    const int E = in_sizes[1] / 2;
    const int* src = ei;
    const int* dst = ei + E;

    // workspace layout (16B aligned)
    char* w = (char*)d_ws;
    int*   deg    = (int*)w;   w += (size_t)N * 4;          // 400000
    float* isq    = (float*)w; w += (size_t)N * 4;
    int*   rowp   = (int*)w;   w += (size_t)(N + 4) * 4;    // N+1 used, padded
    int*   cursor = (int*)w;   w += (size_t)N * 4;
    int*   bsum   = (int*)w;   w += 512 * 4;
    int*   boff   = (int*)w;   w += 512 * 4;
    int*   csr    = (int*)w;   w += (size_t)E * 4;          // 12.8 MB
    float* hs     = (float*)w; w += (size_t)N * 64;         // 6.4 MB
    float* z      = (float*)w; w += (size_t)N * 4;
    float* out    = (float*)d_out;

    const int nbN = (N + 255) / 256;       // 391
    hipMemsetAsync(deg, 0, (size_t)N * 4, stream);
    hipMemsetAsync(cursor, 0, (size_t)N * 4, stream);

    k_deg<<<(E + 255) / 256, 256, 0, stream>>>(dst, E, deg);
    k_isq<<<nbN, 256, 0, stream>>>(deg, isq, N);

    k_scan_bsum<<<nbN, 256, 0, stream>>>(deg, N, bsum);
    k_scan_boff<<<1, 512, 0, stream>>>(bsum, nbN, boff);
    k_scan_final<<<nbN, 256, 0, stream>>>(deg, boff, N, E, rowp);
    k_scatter<<<(E + 255) / 256, 256, 0, stream>>>(src, dst, rowp, cursor, csr, E);

    const int ntiles = (N + 15) / 16;
    const int grid1 = ntiles < 2048 ? ntiles : 2048;
    k_lin1<<<grid1, 256, 0, stream>>>(x, W1, isq, hs, N, ntiles);

    k_gather1<<<(N + 15) / 16, 256, 0, stream>>>(rowp, csr, hs, isq, b1, W2, z, N);
    k_gather2<<<nbN, 256, 0, stream>>>(rowp, csr, z, isq, b2, out, N);
}